// Round 18
// baseline (44.267 us; speedup 1.0000x reference)
//
#include <hip/hip_runtime.h>

// ADDA local attention, K=3, dilation=1, head_dim=64.
// q,k,v = [B=8, d=512, H=56, W=56] fp32 (channel-major), out = [B,H,W,512] fp32.
//
// R18: 2-wave blocks on a row pair (y, y+1).
//  pass1: channel-split  — wave w does ch 32w..32w+31 for BOTH rows
//          (keeps R15's 4-k-row sharing), partials exchanged via LDS
//          (each wave writes only the 9 floats its partner needs).
//  pass2: row-split      — wave w owns row y+w's FULL 64-ch 512B output
//          (R13 lesson: never split a pixel's output run).
//  -> 384 loads/wave (vs R15's 640) AND 2x waves (3584 = 3.5/SIMD).
// Invariants: lane=x coalescing, DPP taps, XCD swizzle, zero-padded-unfold
// masking at softmax only, TSTR=36 transpose, full-line output writes.

namespace {

constexpr int HD = 64, HH = 56, WW = 56, HW = HH * WW;
constexpr int CS = HW, DTOT = 512;
constexpr float SCALE = 0.125f;
constexpr int NP   = HH / 2;   // 28 row-pairs
constexpr int TSTR = 36;       // px stride in transpose LDS

// value of this row at x-1 (lane i <- lane i-1): wave_shr:1 = 0x138
__device__ __forceinline__ float tapL(float v) {
  int i = __float_as_int(v);
  return __int_as_float(__builtin_amdgcn_update_dpp(i, i, 0x138, 0xF, 0xF, false));
}
// value of this row at x+1 (lane i <- lane i+1): wave_shl:1 = 0x130
__device__ __forceinline__ float tapR(float v) {
  int i = __float_as_int(v);
  return __int_as_float(__builtin_amdgcn_update_dpp(i, i, 0x130, 0xF, 0xF, false));
}

__global__ __launch_bounds__(128, 4)
void adda_fwd(const float* __restrict__ qg, const float* __restrict__ kg,
              const float* __restrict__ vg, float* __restrict__ outg) {
  // per-wave transpose regions; also reused (earlier in time) for the
  // partial-logit exchange (wave w outbox at [w*2304 .. w*2304+576))
  __shared__ float tbuf[2 * 64 * TSTR];   // 18432 B

  // XCD-aware bijective swizzle (nwg = 1792 = 8*224)
  int wg = (int)blockIdx.x;
  const int nwg = (int)gridDim.x;
  if ((nwg & 7) == 0) wg = (wg & 7) * (nwg >> 3) + (wg >> 3);

  const int pair = wg % NP;
  const int bh   = wg / NP;              // b*8 + head
  const int l    = (int)threadIdx.x & 63;
  const int wv   = (int)threadIdx.x >> 6;  // 0,1
  const int y    = pair * 2;             // rows y, y+1
  const int yr   = y + wv;               // this wave's OUTPUT row
  const int x    = l < WW ? l : WW - 1;  // lanes 56-63 clone x=55 (not stored)

  const long base  = (long)bh * HD * HW;
  const long cbase = base + (long)(wv * 32) * CS;  // pass-1 channel half
  const int gy0 = (y > 0) ? y - 1 : 0;             // clamped; masked below
  const int gy3 = (y + 2 < HH) ? y + 2 : HH - 1;

  // pass-1 pointers (this wave's 32 channels, 4 shared k rows + 2 q rows)
  const float* __restrict__ qp0 = qg + cbase + (long)y * WW + x;
  const float* __restrict__ qp1 = qg + cbase + (long)(y + 1) * WW + x;
  const float* __restrict__ k0p = kg + cbase + (long)gy0 * WW + x;
  const float* __restrict__ k1p = kg + cbase + (long)y * WW + x;
  const float* __restrict__ k2p = kg + cbase + (long)(y + 1) * WW + x;
  const float* __restrict__ k3p = kg + cbase + (long)gy3 * WW + x;

  // pass-2 pointers (own row, ALL 64 channels)
  const int vy0 = (yr > 0) ? yr - 1 : 0;
  const int vy2 = (yr + 1 < HH) ? yr + 1 : HH - 1;
  const float* __restrict__ v0p = vg + base + (long)vy0 * WW + x;
  const float* __restrict__ v1p = vg + base + (long)yr * WW + x;
  const float* __restrict__ v2p = vg + base + (long)vy2 * WW + x;

  float lg[18];
#pragma unroll
  for (int n = 0; n < 18; ++n) lg[n] = 0.f;

  // ---- pass 1: 8-ch slabs, ping-pong (48 loads in flight) ----
  float q0A[8], q1A[8], a0A[8], a1A[8], a2A[8], a3A[8];
  float q0B[8], q1B[8], a0B[8], a1B[8], a2B[8], a3B[8];

#define LOADK(S, cb)                                    \
  _Pragma("unroll") for (int i = 0; i < 8; ++i) {       \
    q0##S[i] = qp0[((cb) + i) * CS];                    \
    q1##S[i] = qp1[((cb) + i) * CS];                    \
    a0##S[i] = k0p[((cb) + i) * CS];                    \
    a1##S[i] = k1p[((cb) + i) * CS];                    \
    a2##S[i] = k2p[((cb) + i) * CS];                    \
    a3##S[i] = k3p[((cb) + i) * CS];                    \
  }
#define CONSK(S)                                        \
  _Pragma("unroll") for (int i = 0; i < 8; ++i) {       \
    const float t0l = tapL(a0##S[i]), t0r = tapR(a0##S[i]); \
    const float t1l = tapL(a1##S[i]), t1r = tapR(a1##S[i]); \
    const float t2l = tapL(a2##S[i]), t2r = tapR(a2##S[i]); \
    const float t3l = tapL(a3##S[i]), t3r = tapR(a3##S[i]); \
    const float q0 = q0##S[i], q1 = q1##S[i];           \
    lg[0]  = fmaf(q0, t0l,      lg[0]);                 \
    lg[1]  = fmaf(q0, a0##S[i], lg[1]);                 \
    lg[2]  = fmaf(q0, t0r,      lg[2]);                 \
    lg[3]  = fmaf(q0, t1l,      lg[3]);                 \
    lg[4]  = fmaf(q0, a1##S[i], lg[4]);                 \
    lg[5]  = fmaf(q0, t1r,      lg[5]);                 \
    lg[6]  = fmaf(q0, t2l,      lg[6]);                 \
    lg[7]  = fmaf(q0, a2##S[i], lg[7]);                 \
    lg[8]  = fmaf(q0, t2r,      lg[8]);                 \
    lg[9]  = fmaf(q1, t1l,      lg[9]);                 \
    lg[10] = fmaf(q1, a1##S[i], lg[10]);                \
    lg[11] = fmaf(q1, t1r,      lg[11]);                \
    lg[12] = fmaf(q1, t2l,      lg[12]);                \
    lg[13] = fmaf(q1, a2##S[i], lg[13]);                \
    lg[14] = fmaf(q1, t2r,      lg[14]);                \
    lg[15] = fmaf(q1, t3l,      lg[15]);                \
    lg[16] = fmaf(q1, a3##S[i], lg[16]);                \
    lg[17] = fmaf(q1, t3r,      lg[17]);                \
  }

  float b0A[8], b1A[8], b2A[8];
  float b0B[8], b1B[8], b2B[8];
#define LOADV(S, cb)                                    \
  _Pragma("unroll") for (int i = 0; i < 8; ++i) {       \
    b0##S[i] = v0p[((cb) + i) * CS];                    \
    b1##S[i] = v1p[((cb) + i) * CS];                    \
    b2##S[i] = v2p[((cb) + i) * CS];                    \
  }

  LOADK(A, 0);
  LOADK(B, 8);  CONSK(A);
  LOADK(A, 16); CONSK(B);
  LOADK(B, 24); CONSK(A);
                CONSK(B);
  // v slabs issued now: latency hides under exchange + softmax
  LOADV(A, 0);
  LOADV(B, 8);

  // ---- exchange: each wave writes the 9 partials its PARTNER needs ----
  // wave0 writes lg[9..17] (row y+1), wave1 writes lg[0..8] (row y).
  {
    float* outbox = &tbuf[wv * 2304];
    const int src = wv ? 0 : 9;
#pragma unroll
    for (int n = 0; n < 9; ++n) outbox[n * 64 + l] = lg[src + n];
  }
  __syncthreads();
  {
    const float* inbox = &tbuf[(wv ^ 1) * 2304];
    const int dst = wv ? 9 : 0;
#pragma unroll
    for (int n = 0; n < 9; ++n) lg[dst + n] += inbox[n * 64 + l];
  }
  __syncthreads();   // protect tbuf before transpose reuse

  // ---- softmax for OWN row (zero-padded unfold: OOB logit = exact 0) ----
  const bool okl = x > 0, okr = x < WW - 1;
  const bool vt = wv ? true : (y > 0);          // top neighbor valid
  const bool vb = wv ? (y + 2 < HH) : true;     // bottom neighbor valid
  const bool ok[9] = {vt && okl, vt, vt && okr,
                      okl,       true, okr,
                      vb && okl, vb, vb && okr};
  const int lo = wv * 9;
  float w[9];
  float mx = 0.f;
#pragma unroll
  for (int n = 0; n < 9; ++n) { w[n] = ok[n] ? lg[lo + n] * SCALE : 0.f; mx = fmaxf(mx, w[n]); }
  float sum = 0.f;
#pragma unroll
  for (int n = 0; n < 9; ++n) { w[n] = __expf(w[n] - mx); sum += w[n]; }
  const float inv = 1.f / sum;
#pragma unroll
  for (int n = 0; n < 9; ++n) w[n] = ok[n] ? w[n] * inv : 0.f;  // OOB v = 0

  // ---- pass 2: own row, all 64 ch, 8-ch slabs; transpose store ----
  float* __restrict__ tw = &tbuf[wv * 64 * TSTR];
  float* __restrict__ ob =
      outg + ((long)(bh >> 3) * HW + (long)yr * WW) * DTOT + (bh & 7) * HD;

#define CONSV(S, sl)                                    \
  {                                                     \
    float o[8];                                         \
    _Pragma("unroll") for (int i = 0; i < 8; ++i) {     \
      const float t0l = tapL(b0##S[i]), t0r = tapR(b0##S[i]); \
      const float t1l = tapL(b1##S[i]), t1r = tapR(b1##S[i]); \
      const float t2l = tapL(b2##S[i]), t2r = tapR(b2##S[i]); \
      float a = w[0] * t0l;                             \
      a = fmaf(w[1], b0##S[i], a);                      \
      a = fmaf(w[2], t0r, a);                           \
      a = fmaf(w[3], t1l, a);                           \
      a = fmaf(w[4], b1##S[i], a);                      \
      a = fmaf(w[5], t1r, a);                           \
      a = fmaf(w[6], t2l, a);                           \
      a = fmaf(w[7], b2##S[i], a);                      \
      a = fmaf(w[8], t2r, a);                           \
      o[i] = a;                                         \
    }                                                   \
    *(float4*)&tw[l * TSTR + (sl) * 8]     = make_float4(o[0], o[1], o[2], o[3]); \
    *(float4*)&tw[l * TSTR + (sl) * 8 + 4] = make_float4(o[4], o[5], o[6], o[7]); \
  }
  // read-out of one 32-ch run: 56 px x 8 f4 = 448 f4 = 7 exact rounds
#define READOUT(ch0)                                    \
  _Pragma("unroll") for (int r = 0; r < 7; ++r) {       \
    const int g = r * 64 + l;                           \
    const int pxl = g >> 3, slot = g & 7;               \
    const float4 tv = *(const float4*)&tw[pxl * TSTR + slot * 4]; \
    *(float4*)(ob + (long)pxl * DTOT + (ch0) + slot * 4) = tv;    \
  }

  CONSV(A, 0); LOADV(A, 16);
  CONSV(B, 1); LOADV(B, 24);
  CONSV(A, 2); LOADV(A, 32);
  CONSV(B, 3); LOADV(B, 40);
  READOUT(0);
  CONSV(A, 0); LOADV(A, 48);
  CONSV(B, 1); LOADV(B, 56);
  CONSV(A, 2);
  CONSV(B, 3);
  READOUT(32);

#undef LOADK
#undef CONSK
#undef LOADV
#undef CONSV
#undef READOUT
}

} // namespace

extern "C" void kernel_launch(void* const* d_in, const int* in_sizes, int n_in,
                              void* d_out, int out_size, void* d_ws, size_t ws_size,
                              hipStream_t stream) {
  const float* q = (const float*)d_in[0];
  const float* k = (const float*)d_in[1];
  const float* v = (const float*)d_in[2];
  float* out = (float*)d_out;

  const int BH = in_sizes[0] / (HD * HW);  // B * 8 heads = 64
  dim3 grid(BH * NP);                       // 1792 = 8 * 224
  adda_fwd<<<grid, 128, 0, stream>>>(q, k, v, out);
}

// Round 20
// 35.394 us; speedup vs baseline: 1.2507x; 1.2507x over previous
//
#include <hip/hip_runtime.h>

// ADDA local attention, K=3, dilation=1, head_dim=64.
// q,k,v = [B=8, d=512, H=56, W=56] fp32 (channel-major), out = [B,H,W,512] fp32.
//
// R20 = R19 (float2-widened loads, 320 VMEM/wave) with the tbuf geometry
// bug fixed: TSTR=36 (16B-aligned rows) and pass-2 split into two 32-ch
// halves (slab j<16 <=> channel 2j+hs < 32), each with its own READOUT —
// the R15-proven transpose/write path. R19's TSTR=33 held only 33 floats
// per pixel but stored c<=63 -> cross-pixel trample (absmax 4.3).
//
//  lane = (channel parity) x (28 pixel-pairs); every q/k/v access is ONE
//  float2 covering 2 pixels. Cross-parity logit reduction: 36 __shfl.
//  DPP x-taps; group-edge leakage only reaches softmax-masked taps.
// Invariants: 2-row waves share 4 k/v rows; XCD swizzle; wave owns each
// pixel's full 512B output; zero-padded-unfold masking at softmax only.

namespace {

constexpr int HD = 64, HH = 56, WW = 56, HW = HH * WW;
constexpr int CS = HW, DTOT = 512;
constexpr float SCALE = 0.125f;
constexpr int NP   = HH / 2;   // 28 row-pairs
constexpr int TSTR = 36;       // px stride in transpose LDS (144B = 9x16B)

// value of this row at x-1 (lane i <- lane i-1): wave_shr:1 = 0x138
__device__ __forceinline__ float tapLf(float v) {
  int i = __float_as_int(v);
  return __int_as_float(__builtin_amdgcn_update_dpp(i, i, 0x138, 0xF, 0xF, false));
}
// value of this row at x+1 (lane i <- lane i+1): wave_shl:1 = 0x130
__device__ __forceinline__ float tapRf(float v) {
  int i = __float_as_int(v);
  return __int_as_float(__builtin_amdgcn_update_dpp(i, i, 0x130, 0xF, 0xF, false));
}

__global__ __launch_bounds__(64, 2)
void adda_fwd(const float* __restrict__ qg, const float* __restrict__ kg,
              const float* __restrict__ vg, float* __restrict__ outg) {
  __shared__ float tbuf[112 * TSTR];   // 16128 B: [rowsel*56+px][32ch half]

  // XCD-aware bijective swizzle (nwg = 1792 = 8*224)
  int wg = (int)blockIdx.x;
  const int nwg = (int)gridDim.x;
  if ((nwg & 7) == 0) wg = (wg & 7) * (nwg >> 3) + (wg >> 3);

  const int pair = wg % NP;
  const int bh   = wg / NP;             // b*8 + head
  const int l    = (int)threadIdx.x;    // 0..63
  const int y    = pair * 2;            // output rows y, y+1
  const int m    = (l < 28) ? l : ((l < 56) ? l - 28 : l - 56);  // px-pair
  const int hs   = (l < 28) ? 0 : 1;    // channel parity
  const int x0   = 2 * m;               // this lane's pixels: x0, x0+1

  const long base = (long)bh * HD * HW + (long)hs * CS;
  const int gy0 = (y > 0) ? y - 1 : 0;           // clamped; masked below
  const int gy3 = (y + 2 < HH) ? y + 2 : HH - 1;

  const float* __restrict__ qp0 = qg + base + (long)y * WW + x0;
  const float* __restrict__ qp1 = qg + base + (long)(y + 1) * WW + x0;
  const float* __restrict__ k0p = kg + base + (long)gy0 * WW + x0;
  const float* __restrict__ k1p = kg + base + (long)y * WW + x0;
  const float* __restrict__ k2p = kg + base + (long)(y + 1) * WW + x0;
  const float* __restrict__ k3p = kg + base + (long)gy3 * WW + x0;
  const float* __restrict__ v0p = vg + base + (long)gy0 * WW + x0;
  const float* __restrict__ v1p = vg + base + (long)y * WW + x0;
  const float* __restrict__ v2p = vg + base + (long)(y + 1) * WW + x0;
  const float* __restrict__ v3p = vg + base + (long)gy3 * WW + x0;

  // logits: yr0px0=0..8, yr0px1=9..17, yr1px0=18..26, yr1px1=27..35
  float lg[36];
#pragma unroll
  for (int n = 0; n < 36; ++n) lg[n] = 0.f;

  // ---- 8-channel (4-pair) slabs, ping-pong: 24 f2 loads per slab ----
  float2 q0A[4], q1A[4], a0A[4], a1A[4], a2A[4], a3A[4];
  float2 q0B[4], q1B[4], a0B[4], a1B[4], a2B[4], a3B[4];

#define LOADK(S, cb)                                    \
  _Pragma("unroll") for (int i = 0; i < 4; ++i) {       \
    const int co = ((cb) + i) * 2 * CS;                 \
    q0##S[i] = *(const float2*)(qp0 + co);              \
    q1##S[i] = *(const float2*)(qp1 + co);              \
    a0##S[i] = *(const float2*)(k0p + co);              \
    a1##S[i] = *(const float2*)(k1p + co);              \
    a2##S[i] = *(const float2*)(k2p + co);              \
    a3##S[i] = *(const float2*)(k3p + co);              \
  }
#define CONSK(S)                                        \
  _Pragma("unroll") for (int i = 0; i < 4; ++i) {       \
    const float2 q0 = q0##S[i], q1 = q1##S[i];          \
    const float tl0 = tapLf(a0##S[i].y), tr0 = tapRf(a0##S[i].x); \
    const float tl1 = tapLf(a1##S[i].y), tr1 = tapRf(a1##S[i].x); \
    const float tl2 = tapLf(a2##S[i].y), tr2 = tapRf(a2##S[i].x); \
    const float tl3 = tapLf(a3##S[i].y), tr3 = tapRf(a3##S[i].x); \
    lg[0]  = fmaf(q0.x, tl0,        lg[0]);             \
    lg[1]  = fmaf(q0.x, a0##S[i].x, lg[1]);             \
    lg[2]  = fmaf(q0.x, a0##S[i].y, lg[2]);             \
    lg[9]  = fmaf(q0.y, a0##S[i].x, lg[9]);             \
    lg[10] = fmaf(q0.y, a0##S[i].y, lg[10]);            \
    lg[11] = fmaf(q0.y, tr0,        lg[11]);            \
    lg[3]  = fmaf(q0.x, tl1,        lg[3]);             \
    lg[4]  = fmaf(q0.x, a1##S[i].x, lg[4]);             \
    lg[5]  = fmaf(q0.x, a1##S[i].y, lg[5]);             \
    lg[12] = fmaf(q0.y, a1##S[i].x, lg[12]);            \
    lg[13] = fmaf(q0.y, a1##S[i].y, lg[13]);            \
    lg[14] = fmaf(q0.y, tr1,        lg[14]);            \
    lg[18] = fmaf(q1.x, tl1,        lg[18]);            \
    lg[19] = fmaf(q1.x, a1##S[i].x, lg[19]);            \
    lg[20] = fmaf(q1.x, a1##S[i].y, lg[20]);            \
    lg[27] = fmaf(q1.y, a1##S[i].x, lg[27]);            \
    lg[28] = fmaf(q1.y, a1##S[i].y, lg[28]);            \
    lg[29] = fmaf(q1.y, tr1,        lg[29]);            \
    lg[6]  = fmaf(q0.x, tl2,        lg[6]);             \
    lg[7]  = fmaf(q0.x, a2##S[i].x, lg[7]);             \
    lg[8]  = fmaf(q0.x, a2##S[i].y, lg[8]);             \
    lg[15] = fmaf(q0.y, a2##S[i].x, lg[15]);            \
    lg[16] = fmaf(q0.y, a2##S[i].y, lg[16]);            \
    lg[17] = fmaf(q0.y, tr2,        lg[17]);            \
    lg[21] = fmaf(q1.x, tl2,        lg[21]);            \
    lg[22] = fmaf(q1.x, a2##S[i].x, lg[22]);            \
    lg[23] = fmaf(q1.x, a2##S[i].y, lg[23]);            \
    lg[30] = fmaf(q1.y, a2##S[i].x, lg[30]);            \
    lg[31] = fmaf(q1.y, a2##S[i].y, lg[31]);            \
    lg[32] = fmaf(q1.y, tr2,        lg[32]);            \
    lg[24] = fmaf(q1.x, tl3,        lg[24]);            \
    lg[25] = fmaf(q1.x, a3##S[i].x, lg[25]);            \
    lg[26] = fmaf(q1.x, a3##S[i].y, lg[26]);            \
    lg[33] = fmaf(q1.y, a3##S[i].x, lg[33]);            \
    lg[34] = fmaf(q1.y, a3##S[i].y, lg[34]);            \
    lg[35] = fmaf(q1.y, tr3,        lg[35]);            \
  }

  float2 b0A[4], b1A[4], b2A[4], b3A[4];
  float2 b0B[4], b1B[4], b2B[4], b3B[4];
#define LOADV(S, cb)                                    \
  _Pragma("unroll") for (int i = 0; i < 4; ++i) {       \
    const int co = ((cb) + i) * 2 * CS;                 \
    b0##S[i] = *(const float2*)(v0p + co);              \
    b1##S[i] = *(const float2*)(v1p + co);              \
    b2##S[i] = *(const float2*)(v2p + co);              \
    b3##S[i] = *(const float2*)(v3p + co);              \
  }

  // ---- pass 1: 8 k slabs ----
  LOADK(A, 0);  LOADK(B, 4);
  CONSK(A); LOADK(A, 8);
  CONSK(B); LOADK(B, 12);
  CONSK(A); LOADK(A, 16);
  CONSK(B); LOADK(B, 20);
  CONSK(A); LOADK(A, 24);
  CONSK(B); LOADK(B, 28);
  CONSK(A); LOADV(A, 0);   // v prologue hides under shfl+softmax
  CONSK(B); LOADV(B, 4);

  // ---- cross-parity reduction: partner lane has the other channel set ----
  const int partner = (l < 28) ? (l + 28) : (l - 28);
#pragma unroll
  for (int n = 0; n < 36; ++n) lg[n] += __shfl(lg[n], partner, 64);

  // ---- 4 softmaxes (2 px x 2 rows); zero-padded unfold => OOB logit = 0 ----
  const bool okt = y > 0, okb = (y + 2) < HH;
  const bool oklp0 = m > 0, okrp1 = m < 27;
#pragma unroll
  for (int yr = 0; yr < 2; ++yr) {
#pragma unroll
    for (int px = 0; px < 2; ++px) {
      const int o9 = (yr * 2 + px) * 9;
      const bool tok = yr ? true : okt;
      const bool bok = yr ? okb : true;
      const bool lok = px ? true : oklp0;
      const bool rok = px ? okrp1 : true;
      const bool ok[9] = {tok && lok, tok, tok && rok,
                          lok,        true, rok,
                          bok && lok, bok, bok && rok};
      float mx = 0.f;
#pragma unroll
      for (int n = 0; n < 9; ++n) {
        const float vv = ok[n] ? lg[o9 + n] * SCALE : 0.f;
        lg[o9 + n] = vv;
        mx = fmaxf(mx, vv);
      }
      float sum = 0.f;
#pragma unroll
      for (int n = 0; n < 9; ++n) { lg[o9 + n] = __expf(lg[o9 + n] - mx); sum += lg[o9 + n]; }
      const float inv = 1.f / sum;
#pragma unroll
      for (int n = 0; n < 9; ++n)
        lg[o9 + n] = ok[n] ? lg[o9 + n] * inv : 0.f;   // OOB v contributes 0
    }
  }

  // ---- pass 2: v slabs; 32-ch halves; scalar tbuf writes (lanes < 56) ----
#define CONSV(S, cb, ch0)                               \
  _Pragma("unroll") for (int i = 0; i < 4; ++i) {       \
    const float tl0 = tapLf(b0##S[i].y), tr0 = tapRf(b0##S[i].x); \
    const float tl1 = tapLf(b1##S[i].y), tr1 = tapRf(b1##S[i].x); \
    const float tl2 = tapLf(b2##S[i].y), tr2 = tapRf(b2##S[i].x); \
    const float tl3 = tapLf(b3##S[i].y), tr3 = tapRf(b3##S[i].x); \
    float o00 = lg[0] * tl0;                            \
    o00 = fmaf(lg[1], b0##S[i].x, o00);                 \
    o00 = fmaf(lg[2], b0##S[i].y, o00);                 \
    o00 = fmaf(lg[3], tl1, o00);                        \
    o00 = fmaf(lg[4], b1##S[i].x, o00);                 \
    o00 = fmaf(lg[5], b1##S[i].y, o00);                 \
    o00 = fmaf(lg[6], tl2, o00);                        \
    o00 = fmaf(lg[7], b2##S[i].x, o00);                 \
    o00 = fmaf(lg[8], b2##S[i].y, o00);                 \
    float o01 = lg[9] * b0##S[i].x;                     \
    o01 = fmaf(lg[10], b0##S[i].y, o01);                \
    o01 = fmaf(lg[11], tr0, o01);                       \
    o01 = fmaf(lg[12], b1##S[i].x, o01);                \
    o01 = fmaf(lg[13], b1##S[i].y, o01);                \
    o01 = fmaf(lg[14], tr1, o01);                       \
    o01 = fmaf(lg[15], b2##S[i].x, o01);                \
    o01 = fmaf(lg[16], b2##S[i].y, o01);                \
    o01 = fmaf(lg[17], tr2, o01);                       \
    float o10 = lg[18] * tl1;                           \
    o10 = fmaf(lg[19], b1##S[i].x, o10);                \
    o10 = fmaf(lg[20], b1##S[i].y, o10);                \
    o10 = fmaf(lg[21], tl2, o10);                       \
    o10 = fmaf(lg[22], b2##S[i].x, o10);                \
    o10 = fmaf(lg[23], b2##S[i].y, o10);                \
    o10 = fmaf(lg[24], tl3, o10);                       \
    o10 = fmaf(lg[25], b3##S[i].x, o10);                \
    o10 = fmaf(lg[26], b3##S[i].y, o10);                \
    float o11 = lg[27] * b1##S[i].x;                    \
    o11 = fmaf(lg[28], b1##S[i].y, o11);                \
    o11 = fmaf(lg[29], tr1, o11);                       \
    o11 = fmaf(lg[30], b2##S[i].x, o11);                \
    o11 = fmaf(lg[31], b2##S[i].y, o11);                \
    o11 = fmaf(lg[32], tr2, o11);                       \
    o11 = fmaf(lg[33], b3##S[i].x, o11);                \
    o11 = fmaf(lg[34], b3##S[i].y, o11);                \
    o11 = fmaf(lg[35], tr3, o11);                       \
    if (l < 56) {                                       \
      const int c = ((cb) + i) * 2 + hs - (ch0);        \
      tbuf[x0 * TSTR + c]        = o00;                 \
      tbuf[(x0 + 1) * TSTR + c]  = o01;                 \
      tbuf[(56 + x0) * TSTR + c] = o10;                 \
      tbuf[(57 + x0) * TSTR + c] = o11;                 \
    }                                                   \
  }

  float* __restrict__ ob =
      outg + ((long)(bh >> 3) * HW + (long)y * WW) * DTOT + (bh & 7) * HD;

  // read-out of one 32-ch half: 112 px x 8 f4 = 896 f4 = 14 exact rounds
#define READOUT(ch0)                                    \
  _Pragma("unroll") for (int r = 0; r < 14; ++r) {      \
    const int g = r * 64 + l;                           \
    const int pg = g >> 3, slot = g & 7;                \
    const float4 tv = *(const float4*)&tbuf[pg * TSTR + slot * 4]; \
    *(float4*)(ob + (long)pg * DTOT + (ch0) + slot * 4) = tv;      \
  }

  CONSV(A, 0, 0);   LOADV(A, 8);
  CONSV(B, 4, 0);   LOADV(B, 12);
  CONSV(A, 8, 0);   LOADV(A, 16);
  CONSV(B, 12, 0);  LOADV(B, 20);
  READOUT(0);
  CONSV(A, 16, 32); LOADV(A, 24);
  CONSV(B, 20, 32); LOADV(B, 28);
  CONSV(A, 24, 32);
  CONSV(B, 28, 32);
  READOUT(32);

#undef LOADK
#undef CONSK
#undef LOADV
#undef CONSV
#undef READOUT
}

} // namespace

extern "C" void kernel_launch(void* const* d_in, const int* in_sizes, int n_in,
                              void* d_out, int out_size, void* d_ws, size_t ws_size,
                              hipStream_t stream) {
  const float* q = (const float*)d_in[0];
  const float* k = (const float*)d_in[1];
  const float* v = (const float*)d_in[2];
  float* out = (float*)d_out;

  const int BH = in_sizes[0] / (HD * HW);  // B * 8 heads = 64
  dim3 grid(BH * NP);                       // 1792 = 8 * 224
  adda_fwd<<<grid, 64, 0, stream>>>(q, k, v, out);
}